// Round 12
// baseline (250.535 us; speedup 1.0000x reference)
//
#include <hip/hip_runtime.h>
#include <stdint.h>

typedef unsigned short u16;
typedef unsigned int   u32;
typedef __attribute__((ext_vector_type(8))) short short8;
typedef __attribute__((ext_vector_type(4))) float f32x4;

static constexpr int kN = 16384;
static constexpr float kEPS = 1e-5f;

__device__ __forceinline__ u16 f2bf(float x) {
  u32 u = __float_as_uint(x);
  u32 r = (u + 0x7fffu + ((u >> 16) & 1u)) >> 16;
  return (u16)r;
}
__device__ __forceinline__ float bf2f(u16 x) {
  return __uint_as_float(((u32)x) << 16);
}
__device__ __forceinline__ void ldbf8(const u16* p, float* o) {
  uint4 v = *(const uint4*)p;
  o[0] = __uint_as_float(v.x << 16);  o[1] = __uint_as_float(v.x & 0xffff0000u);
  o[2] = __uint_as_float(v.y << 16);  o[3] = __uint_as_float(v.y & 0xffff0000u);
  o[4] = __uint_as_float(v.z << 16);  o[5] = __uint_as_float(v.z & 0xffff0000u);
  o[6] = __uint_as_float(v.w << 16);  o[7] = __uint_as_float(v.w & 0xffff0000u);
}
__device__ __forceinline__ void gll16(const u16* g, u16* l) {
  __builtin_amdgcn_global_load_lds(
      (const __attribute__((address_space(1))) void*)g,
      (__attribute__((address_space(3))) void*)l, 16, 0, 0);
}

// ================= fused setup: wcast | hist | pbc+W2f | prep =================
// ctl area (cnt/cursor/pS/pQ) is zeroed by hipMemsetAsync BEFORE this dispatch,
// so the hist slice (atomicAdd into cnt) is safe regardless of block order.
struct WSet {
  const float* s[8]; u16* d[8];
  int K[8]; int N[8]; int dstride[8]; int coff[8];
};

__global__ __launch_bounds__(256) void k_setup(WSet ws,
                                               u32* __restrict__ cnt,
                                               const float* __restrict__ proj_b,
                                               const float* __restrict__ pe_b2,
                                               float* __restrict__ pbc,
                                               const float* __restrict__ uw1,
                                               const float* __restrict__ ub1,
                                               const float* __restrict__ uw2,
                                               const float* __restrict__ ub2,
                                               u16* __restrict__ W2f,
                                               float* __restrict__ bbf,
                                               const int* __restrict__ coords,
                                               const float* __restrict__ feats,
                                               const float* __restrict__ pw1,
                                               const float* __restrict__ pb1,
                                               u16* __restrict__ A1,
                                               u16* __restrict__ A2) {
  int w = blockIdx.y;
  if (w == 8) {  // hist: one point per thread (cnt pre-zeroed by memset)
    int n = blockIdx.x * 256 + threadIdx.x;
    if (n < kN) {
      int c = coords[n * 3] * 128 + coords[n * 3 + 1];
      atomicAdd(&cnt[c], 1u);
    }
    return;
  }
  if (w == 9) {  // pbc + fused tail weight
    int bx = blockIdx.x;
    if (bx == 0) {
      pbc[threadIdx.x] = proj_b[threadIdx.x] + pe_b2[threadIdx.x];
    } else if (bx < 65) {
      int n = bx - 1;          // 0..63
      int k = threadIdx.x;     // 0..255
      float s = 0.f;
      for (int j = 0; j < 64; j++) s += uw1[k * 64 + j] * uw2[(64 + j) * 64 + n];
      W2f[n * 320 + k] = f2bf(s);
      if (k < 64) W2f[n * 320 + 256 + k] = f2bf(uw2[k * 64 + n]);
      if (k == 0) {
        float b = ub2[n];
        for (int j = 0; j < 64; j++) b += ub1[j] * uw2[(64 + j) * 64 + n];
        bbf[n] = b;
      }
    }
    return;
  }
  if (w == 10) {  // prep: A1 = [feats | relu(PE hidden)] (Nx192); A2[:,256:320] = feats bf16
    int r0 = blockIdx.x * 32;
#pragma unroll
    for (int s = 0; s < 3; s++) {
      int j = threadIdx.x + s * 256;  // 0..767 = 32 rows x 24 segs
      int row = j / 24, seg = j % 24;
      int n = r0 + row;
      u16 o[8];
      if (seg < 8) {
        const float* fp = feats + (size_t)n * 64 + seg * 8;
        float4 a = *(const float4*)fp;
        float4 b = *(const float4*)(fp + 4);
        o[0] = f2bf(a.x); o[1] = f2bf(a.y); o[2] = f2bf(a.z); o[3] = f2bf(a.w);
        o[4] = f2bf(b.x); o[5] = f2bf(b.y); o[6] = f2bf(b.z); o[7] = f2bf(b.w);
        *(uint4*)(A2 + (size_t)n * 320 + 256 + seg * 8) = *(uint4*)o;
      } else {
        int jj0 = (seg - 8) * 8;
        float x0 = (float)coords[n * 3 + 0] * (1.f / 127.f);
        float x1 = (float)coords[n * 3 + 1] * (1.f / 127.f);
        float x2 = (float)coords[n * 3 + 2] * (1.f / 127.f);
#pragma unroll
        for (int u = 0; u < 8; u++) {
          int jj = jj0 + u;
          float hv = pb1[jj] + x0 * pw1[jj] + x1 * pw1[128 + jj] + x2 * pw1[256 + jj];
          o[u] = f2bf(fmaxf(hv, 0.f));
        }
      }
      *(uint4*)(A1 + (size_t)n * 192 + seg * 8) = *(uint4*)o;
    }
    return;
  }
  // weight cast+transpose: S (K x N fp32) -> D[n*dstride+coff+k] bf16
  const float* S = ws.s[w]; u16* D = ws.d[w];
  int K = ws.K[w], N = ws.N[w], ds = ws.dstride[w], co = ws.coff[w];
  int ntx = N >> 5, tiles = ntx * (K >> 5);
  int t = blockIdx.x;
  if (t >= tiles) return;
  int n0 = (t % ntx) * 32, k0 = (t / ntx) * 32;
  __shared__ float st[32][33];
  int tr = threadIdx.x >> 3, tc4 = (threadIdx.x & 7) * 4;
  float4 v = *(const float4*)(S + (size_t)(k0 + tr) * N + n0 + tc4);
  st[tc4 + 0][tr] = v.x; st[tc4 + 1][tr] = v.y;
  st[tc4 + 2][tr] = v.z; st[tc4 + 3][tr] = v.w;
  __syncthreads();
  u16 o4[4];
  o4[0] = f2bf(st[tr][tc4 + 0]); o4[1] = f2bf(st[tr][tc4 + 1]);
  o4[2] = f2bf(st[tr][tc4 + 2]); o4[3] = f2bf(st[tr][tc4 + 3]);
  *(uint2*)(D + (size_t)(n0 + tr) * ds + co + k0 + tc4) = *(uint2*)o4;
}

// ================= neighbor grid (cells = x*128+y) =================

__global__ __launch_bounds__(256) void k_scan(const u32* __restrict__ cnt,
                                              u32* __restrict__ startb) {
  __shared__ u32 tots[256];
  int t = threadIdx.x;
  int base = t * 64;
  u32 s = 0;
  for (int i = 0; i < 64; i++) s += cnt[base + i];
  tots[t] = s;
  __syncthreads();
  if (t == 0) {
    u32 run = 0;
    for (int i = 0; i < 256; i++) { u32 v = tots[i]; tots[i] = run; run += v; }
  }
  __syncthreads();
  u32 run = tots[t];
  for (int i = 0; i < 64; i++) { startb[base + i] = run; run += cnt[base + i]; }
}

__global__ __launch_bounds__(256) void k_scatter(const int* __restrict__ coords,
                                                 const u32* __restrict__ startb,
                                                 u32* __restrict__ cursor,
                                                 u32* __restrict__ pts) {
  int n = blockIdx.x * 256 + threadIdx.x;
  int x = coords[n * 3], y = coords[n * 3 + 1], z = coords[n * 3 + 2];
  int c = x * 128 + y;
  u32 slot = atomicAdd(&cursor[c], 1u);
  pts[startb[c] + slot] = ((u32)z << 14) | (u32)n;  // z:7b | idx:14b
}

__global__ __launch_bounds__(256) void k_select(const int* __restrict__ coords,
                                                const u32* __restrict__ startb,
                                                const u32* __restrict__ cnt,
                                                const u32* __restrict__ pts,
                                                int* __restrict__ idxo) {
  int n = blockIdx.x * 256 + threadIdx.x;
  int x = coords[n * 3], y = coords[n * 3 + 1], z = coords[n * 3 + 2];
  u32 best[16];
#pragma unroll
  for (int j = 0; j < 16; j++) best[j] = 0xFFFFFFFFu;
  const int dxs[13] = {0, -1, 1, 0, 0, -2, 2, 0, 0, -1, -1, 1, 1};
  const int dys[13] = {0, 0, 0, -1, 1, 0, 0, -2, 2, -1, 1, -1, 1};
  const int dbs[13] = {0, 1, 1, 1, 1, 2, 2, 2, 2, 2, 2, 2, 2};
#pragma unroll
  for (int t = 0; t < 13; t++) {
    int xx = x + dxs[t], yy = y + dys[t];
    if (xx < 0 || xx > 127 || yy < 0 || yy > 127) continue;
    int c = xx * 128 + yy;
    u32 s0 = startb[c], e0 = s0 + cnt[c];
    for (u32 i = s0; i < e0; ++i) {
      u32 p = pts[i];
      int zq = (int)(p >> 14);
      int id = (int)(p & 16383u);
      int az = z - zq; az = az < 0 ? -az : az;
      int dd = dbs[t] + az;
      u32 key = (dd <= 2) ? (((u32)dd << 14) | (u32)id) : 0xFFFFFFFFu;
#pragma unroll
      for (int j = 0; j < 16; j++) {
        u32 lo = min(best[j], key);
        u32 hi = max(best[j], key);
        best[j] = lo; key = hi;
      }
    }
  }
#pragma unroll
  for (int j = 0; j < 16; j++)
    idxo[n * 16 + j] = (best[j] == 0xFFFFFFFFu) ? -1 : (int)(best[j] & 16383u);
}

// ================= bf16 MFMA GEMM: C = A(MxK) @ WT(NxK)^T =================
// 64x64 tile, BK=64 via paired 32-chunk staging buffers.
// 256 threads (4 waves 2x2). OUTBF: 1=bf16. ADD: += bf16 Addp. K % 64 == 0.
template <int ACT, int OUTBF, int ADD>
__global__ __launch_bounds__(256) void k_mfma_gemm(
    const u16* __restrict__ A, const u16* __restrict__ WT,
    const float* __restrict__ bias,
    void* __restrict__ Cout,
    const u16* __restrict__ Addp,
    int M, int K, int N) {
  __shared__ __align__(16) u16 As[2][64 * 32];
  __shared__ __align__(16) u16 Bs[2][64 * 32];
  const int tid = threadIdx.x;
  const int wave = tid >> 6, lane = tid & 63;
  const int bm = blockIdx.y * 64, bn = blockIdx.x * 64;
  const int wr = (wave >> 1) * 32, wc = (wave & 1) * 32;
  const int g = wave * 64 + lane;
  const int grow = g >> 2, gko = (g & 3) * 8;
  const int fr = lane & 15, fk = (lane >> 4) * 8, rq = (lane >> 4) * 4;

  f32x4 acc[2][2];
#pragma unroll
  for (int i = 0; i < 2; i++)
#pragma unroll
    for (int j = 0; j < 2; j++)
#pragma unroll
      for (int r = 0; r < 4; r++) acc[i][j][r] = 0.f;

  for (int k0 = 0; k0 < K; k0 += 64) {
#pragma unroll
    for (int h = 0; h < 2; h++) {
      gll16(A + (size_t)(bm + grow) * K + k0 + h * 32 + gko, As[h] + g * 8);
      gll16(WT + (size_t)(bn + grow) * K + k0 + h * 32 + gko, Bs[h] + g * 8);
    }
    __syncthreads();
#pragma unroll
    for (int h = 0; h < 2; h++) {
      short8 af[2], bg[2];
#pragma unroll
      for (int i = 0; i < 2; i++)
        af[i] = *(const short8*)&As[h][(wr + i * 16 + fr) * 32 + fk];
#pragma unroll
      for (int j = 0; j < 2; j++)
        bg[j] = *(const short8*)&Bs[h][(wc + j * 16 + fr) * 32 + fk];
#pragma unroll
      for (int i = 0; i < 2; i++)
#pragma unroll
        for (int j = 0; j < 2; j++)
          acc[i][j] = __builtin_amdgcn_mfma_f32_16x16x32_bf16(af[i], bg[j], acc[i][j], 0, 0, 0);
    }
    __syncthreads();
  }

#pragma unroll
  for (int j = 0; j < 2; j++) {
    int cc = bn + wc + j * 16 + fr;
    float bval = bias ? bias[cc] : 0.f;
#pragma unroll
    for (int i = 0; i < 2; i++) {
      int rbase = bm + wr + i * 16 + rq;
#pragma unroll
      for (int r = 0; r < 4; r++) {
        float v = acc[i][j][r] + bval;
        size_t o = (size_t)(rbase + r) * N + cc;
        if (ADD) v += bf2f(Addp[o]);
        if (ACT) v = fmaxf(v, 0.f);
        if (OUTBF) ((u16*)Cout)[o] = f2bf(v);
        else       ((float*)Cout)[o] = v;
      }
    }
  }
}

// ================= attention: one thread per (query, head), cell-sorted order =================
__global__ __launch_bounds__(256) void k_attn(const u16* __restrict__ QKV,
                                              const u32* __restrict__ pts,
                                              const int* __restrict__ idx,
                                              const float* __restrict__ bq,
                                              const float* __restrict__ bk,
                                              const float* __restrict__ bv,
                                              u16* __restrict__ outp) {
  int gid = blockIdx.x * 256 + threadIdx.x;
  int n = (int)(pts[gid >> 3] & 16383u), h = gid & 7;
  const int* ip = idx + n * 16;
  const int hb = h * 32;
  float q[32];
  {
    int i0 = ip[0];  // slot0: dist 0 — always valid
    const u16* qp = QKV + (size_t)i0 * 768 + hb;
#pragma unroll
    for (int j = 0; j < 32; j += 8) ldbf8(qp + j, &q[j]);
#pragma unroll
    for (int j = 0; j < 32; j++) q[j] += bq[hb + j];
  }
  float qbk = 0.f;
#pragma unroll
  for (int j = 0; j < 32; j++) qbk += q[j] * bk[hb + j];
  float s[16]; int ii[16];
#pragma unroll
  for (int m = 0; m < 16; m++) {
    int i = ip[m]; ii[m] = i;
    float d = qbk;
    if (i >= 0) {
      const u16* kp = QKV + (size_t)i * 768 + 256 + hb;
      float kv[32];
#pragma unroll
      for (int j = 0; j < 32; j += 8) ldbf8(kp + j, &kv[j]);
#pragma unroll
      for (int j = 0; j < 32; j++) d += q[j] * kv[j];
    }
    s[m] = d * 0.17677669529663689f;  // 1/sqrt(32)
  }
  float mx = s[0];
#pragma unroll
  for (int m = 1; m < 16; m++) mx = fmaxf(mx, s[m]);
  float sum = 0.f;
#pragma unroll
  for (int m = 0; m < 16; m++) { s[m] = __expf(s[m] - mx); sum += s[m]; }
  float inv = 1.f / sum;
  float o[32];
#pragma unroll
  for (int j = 0; j < 32; j++) o[j] = 0.f;
#pragma unroll
  for (int m = 0; m < 16; m++) {
    if (ii[m] >= 0) {
      const u16* vp = QKV + (size_t)ii[m] * 768 + 512 + hb;
      float vv[32];
#pragma unroll
      for (int j = 0; j < 32; j += 8) ldbf8(vp + j, &vv[j]);
#pragma unroll
      for (int j = 0; j < 32; j++) o[j] += s[m] * vv[j];
    }
  }
  u16* op = outp + (size_t)n * 256 + hb;
#pragma unroll
  for (int j = 0; j < 32; j += 8) {
    u16 tmp[8];
#pragma unroll
    for (int jj = 0; jj < 8; jj++) tmp[jj] = f2bf(o[j + jj] * inv + bv[hb + j + jj]);
    *(uint4*)(op + j) = *(uint4*)tmp;
  }
}

// ================= layernorm over D=256 (bf16 in), one wave per row, bf16 -> A2[:,0:256] =================
__global__ __launch_bounds__(256) void k_ln(const u16* __restrict__ xx,
                                            const float* __restrict__ g,
                                            const float* __restrict__ b,
                                            u16* __restrict__ A2) {
  int row = blockIdx.x * 4 + (threadIdx.x >> 6);
  int lane = threadIdx.x & 63;
  uint2 raw = *(const uint2*)(xx + (size_t)row * 256 + lane * 4);
  float x0 = __uint_as_float(raw.x << 16), x1 = __uint_as_float(raw.x & 0xffff0000u);
  float x2 = __uint_as_float(raw.y << 16), x3 = __uint_as_float(raw.y & 0xffff0000u);
  float sm = x0 + x1 + x2 + x3;
#pragma unroll
  for (int off = 1; off < 64; off <<= 1) sm += __shfl_xor(sm, off);
  float mu = sm * (1.f / 256.f);
  float d0 = x0 - mu, d1 = x1 - mu, d2 = x2 - mu, d3 = x3 - mu;
  float sq = d0 * d0 + d1 * d1 + d2 * d2 + d3 * d3;
#pragma unroll
  for (int off = 1; off < 64; off <<= 1) sq += __shfl_xor(sq, off);
  float rstd = rsqrtf(sq * (1.f / 256.f) + kEPS);
  float4 gv = *(const float4*)(g + lane * 4);
  float4 bv4 = *(const float4*)(b + lane * 4);
  u16 o[4];
  o[0] = f2bf(d0 * rstd * gv.x + bv4.x); o[1] = f2bf(d1 * rstd * gv.y + bv4.y);
  o[2] = f2bf(d2 * rstd * gv.z + bv4.z); o[3] = f2bf(d3 * rstd * gv.w + bv4.w);
  *(uint2*)(A2 + (size_t)row * 320 + lane * 4) = *(uint2*)o;
}

// ================= f = A2 @ W2f^T + bbf -> fB + fused BN column stats =================
// K = 320 = 5 x 64 exactly.
__global__ __launch_bounds__(256) void k_fgemm(const u16* __restrict__ A2,
                                               const u16* __restrict__ W2f,
                                               const float* __restrict__ bbf,
                                               float* __restrict__ fB,
                                               float* __restrict__ pS,
                                               float* __restrict__ pQ) {
  __shared__ __align__(16) u16 As[2][2048];
  __shared__ __align__(16) u16 Bs[2][2048];
  __shared__ float colS[64][2], colQ[64][2];
  const int tid = threadIdx.x;
  const int wave = tid >> 6, lane = tid & 63;
  const int bm = blockIdx.x * 64;
  const int wr = (wave >> 1) * 32, wc = (wave & 1) * 32;
  const int fr = lane & 15, fk = (lane >> 4) * 8, rq = (lane >> 4) * 4;
  const int g = wave * 64 + lane;
  const int grow = g >> 2, gko = (g & 3) * 8;

  f32x4 acc[2][2];
#pragma unroll
  for (int i = 0; i < 2; i++)
#pragma unroll
    for (int j = 0; j < 2; j++)
#pragma unroll
      for (int r = 0; r < 4; r++) acc[i][j][r] = 0.f;
  for (int k0 = 0; k0 < 320; k0 += 64) {
#pragma unroll
    for (int h = 0; h < 2; h++) {
      gll16(A2 + (size_t)(bm + grow) * 320 + k0 + h * 32 + gko, As[h] + g * 8);
      gll16(W2f + (size_t)grow * 320 + k0 + h * 32 + gko, Bs[h] + g * 8);
    }
    __syncthreads();
#pragma unroll
    for (int h = 0; h < 2; h++) {
      short8 af[2], bg[2];
#pragma unroll
      for (int i = 0; i < 2; i++)
        af[i] = *(const short8*)&As[h][(wr + i * 16 + fr) * 32 + fk];
#pragma unroll
      for (int j = 0; j < 2; j++)
        bg[j] = *(const short8*)&Bs[h][(wc + j * 16 + fr) * 32 + fk];
#pragma unroll
      for (int i = 0; i < 2; i++)
#pragma unroll
        for (int j = 0; j < 2; j++)
          acc[i][j] = __builtin_amdgcn_mfma_f32_16x16x32_bf16(af[i], bg[j], acc[i][j], 0, 0, 0);
    }
    __syncthreads();
  }
  float cS[2] = {0.f, 0.f}, cQ[2] = {0.f, 0.f};
#pragma unroll
  for (int j = 0; j < 2; j++) {
    int col = wc + j * 16 + fr;
    float bv = bbf[col];
#pragma unroll
    for (int i = 0; i < 2; i++) {
      int rbase = bm + wr + i * 16 + rq;
#pragma unroll
      for (int r = 0; r < 4; r++) {
        float v = acc[i][j][r] + bv;
        fB[(size_t)(rbase + r) * 64 + col] = v;
        cS[j] += v; cQ[j] += v * v;
      }
    }
  }
#pragma unroll
  for (int off = 16; off < 64; off <<= 1) {
#pragma unroll
    for (int j = 0; j < 2; j++) {
      cS[j] += __shfl_xor(cS[j], off);
      cQ[j] += __shfl_xor(cQ[j], off);
    }
  }
  if ((lane >> 4) == 0) {
#pragma unroll
    for (int j = 0; j < 2; j++) {
      colS[wc + j * 16 + fr][wave >> 1] = cS[j];
      colQ[wc + j * 16 + fr][wave >> 1] = cQ[j];
    }
  }
  __syncthreads();
  if (tid < 64) {
    atomicAdd(&pS[tid], colS[tid][0] + colS[tid][1]);
    atomicAdd(&pQ[tid], colQ[tid][0] + colQ[tid][1]);
  }
}

// ================= BN finalize (redundant per block, pS/pQ L2-hot) + apply + relu =================
__global__ __launch_bounds__(256) void k_bnapply(const float* __restrict__ f,
                                                 const float* __restrict__ pS,
                                                 const float* __restrict__ pQ,
                                                 const float* __restrict__ g,
                                                 const float* __restrict__ b,
                                                 float* __restrict__ out) {
  __shared__ float cfL[64], shL[64];
  if (threadIdx.x < 64) {
    int c = threadIdx.x;
    float S = pS[c], Q = pQ[c];
    float m = S * (1.f / 16384.f);
    float var = Q * (1.f / 16384.f) - m * m;
    float cf = rsqrtf(var + kEPS) * g[c];
    cfL[c] = cf;
    shL[c] = b[c] - m * cf;
  }
  __syncthreads();
  int gid = blockIdx.x * 256 + threadIdx.x;
  int e = gid * 4, col = e & 63;
  float4 v = *(const float4*)(f + e);
  float4 cf = *(const float4*)&cfL[col];
  float4 sh = *(const float4*)&shL[col];
  float4 o;
  o.x = fmaxf(v.x * cf.x + sh.x, 0.f);
  o.y = fmaxf(v.y * cf.y + sh.y, 0.f);
  o.z = fmaxf(v.z * cf.z + sh.z, 0.f);
  o.w = fmaxf(v.w * cf.w + sh.w, 0.f);
  *(float4*)(out + e) = o;
}

// ================= launch =================
extern "C" void kernel_launch(void* const* d_in, const int* in_sizes, int n_in,
                              void* d_out, int out_size, void* d_ws, size_t ws_size,
                              hipStream_t stream) {
  (void)in_sizes; (void)n_in; (void)out_size; (void)ws_size;
  const int*   coords = (const int*)d_in[0];
  const float* feats  = (const float*)d_in[1];
  const float* pe_w1  = (const float*)d_in[2];
  const float* pe_b1  = (const float*)d_in[3];
  const float* pe_w2  = (const float*)d_in[4];
  const float* pe_b2  = (const float*)d_in[5];
  const float* proj_w = (const float*)d_in[6];
  const float* proj_b = (const float*)d_in[7];
  const float* wq  = (const float*)d_in[8];
  const float* bq  = (const float*)d_in[9];
  const float* wk  = (const float*)d_in[10];
  const float* bk  = (const float*)d_in[11];
  const float* wv  = (const float*)d_in[12];
  const float* bv  = (const float*)d_in[13];
  const float* wo  = (const float*)d_in[14];
  const float* bo  = (const float*)d_in[15];
  const float* fw1 = (const float*)d_in[16];
  const float* fb1 = (const float*)d_in[17];
  const float* fw2 = (const float*)d_in[18];
  const float* fb2 = (const float*)d_in[19];
  const float* lng = (const float*)d_in[20];
  const float* lnb = (const float*)d_in[21];
  const float* uw1 = (const float*)d_in[22];
  const float* ub1 = (const float*)d_in[23];
  const float* uw2 = (const float*)d_in[24];
  const float* ub2 = (const float*)d_in[25];
  const float* bng = (const float*)d_in[26];
  const float* bnb = (const float*)d_in[27];
  float* out = (float*)d_out;

  char* Wc = (char*)d_ws;
  const size_t MB = 1u << 20;
  u16*   A1    = (u16*)(Wc + 0 * MB);    // 6MB
  u16*   srcb  = (u16*)(Wc + 6 * MB);    // 8MB
  u16*   QKVb  = (u16*)(Wc + 14 * MB);   // 24MB
  u16*   aoInB = (u16*)(Wc + 38 * MB);   // 8MB
  u16*   aoB   = (u16*)(Wc + 46 * MB);   // 8MB
  u16*   h1B   = (u16*)(Wc + 54 * MB);   // 16MB
  u16*   xBb   = (u16*)(Wc + 70 * MB);   // 8MB
  u16*   A2    = (u16*)(Wc + 78 * MB);   // 10MB [y | feats]
  float* fB    = (float*)(Wc + 0 * MB);  // 4MB over dead A1

  u16* qkvT  = (u16*)(Wc + 88 * MB);     // 768 x 256
  u16* woT   = qkvT + 196608;            // 256 x 256
  u16* fw1T  = woT + 65536;              // 512 x 256
  u16* fw2T  = fw1T + 131072;            // 256 x 512
  u16* W1T   = fw2T + 131072;            // 256 x 192
  u16* W2f   = W1T + 49152;              // 64 x 320
  float* pbc = (float*)(W2f + 20480);    // 256
  float* bbf = pbc + 256;                // 64

  u32* Z      = (u32*)(Wc + 90 * MB);
  u32* cnt    = Z;                        // 16384  (memset 0)
  u32* cursor = Z + 16384;                // 16384  (memset 0)
  float* pS   = (float*)(Z + 32768);      // 64     (memset 0)
  float* pQ   = (float*)(Z + 32832);      // 64     (memset 0)
  u32* startb = Z + 33280;                // 16384
  u32* pts    = Z + 49664;                // 16384
  int* idxb   = (int*)(Z + 66048);        // N*16

  WSet ws;
  ws.s[0] = wq;     ws.d[0] = qkvT;          ws.K[0] = 256; ws.N[0] = 256; ws.dstride[0] = 256; ws.coff[0] = 0;
  ws.s[1] = wk;     ws.d[1] = qkvT + 65536;  ws.K[1] = 256; ws.N[1] = 256; ws.dstride[1] = 256; ws.coff[1] = 0;
  ws.s[2] = wv;     ws.d[2] = qkvT + 131072; ws.K[2] = 256; ws.N[2] = 256; ws.dstride[2] = 256; ws.coff[2] = 0;
  ws.s[3] = wo;     ws.d[3] = woT;           ws.K[3] = 256; ws.N[3] = 256; ws.dstride[3] = 256; ws.coff[3] = 0;
  ws.s[4] = fw1;    ws.d[4] = fw1T;          ws.K[4] = 256; ws.N[4] = 512; ws.dstride[4] = 256; ws.coff[4] = 0;
  ws.s[5] = fw2;    ws.d[5] = fw2T;          ws.K[5] = 512; ws.N[5] = 256; ws.dstride[5] = 512; ws.coff[5] = 0;
  ws.s[6] = proj_w; ws.d[6] = W1T;           ws.K[6] = 64;  ws.N[6] = 256; ws.dstride[6] = 192; ws.coff[6] = 0;
  ws.s[7] = pe_w2;  ws.d[7] = W1T;           ws.K[7] = 128; ws.N[7] = 256; ws.dstride[7] = 192; ws.coff[7] = 64;

  // 0. zero ctl area (cnt/cursor/pS/pQ) — same-stream ordering precedes k_setup
  hipMemsetAsync(Z, 0, 32896 * sizeof(u32), stream);
  // 1. setup: weight casts | hist | pbc+W2f/bbf | prep(A1 + A2 feats half)
  k_setup<<<dim3(512, 11), 256, 0, stream>>>(ws, cnt, proj_b, pe_b2, pbc,
                                             uw1, ub1, uw2, ub2, W2f, bbf,
                                             coords, feats, pe_w1, pe_b1, A1, A2);
  // 2-4. neighbor pipeline (scan -> scatter -> select)
  k_scan<<<1, 256, 0, stream>>>(cnt, startb);
  k_scatter<<<64, 256, 0, stream>>>(coords, startb, cursor, pts);
  k_select<<<64, 256, 0, stream>>>(coords, startb, cnt, pts, idxb);
  // 5. src = A1 @ W1T^T + pbc (bf16), K=192
  k_mfma_gemm<0, 1, 0><<<dim3(4, 256), 256, 0, stream>>>(A1, W1T, pbc, srcb, nullptr, kN, 192, 256);
  // 6. QKV fused (N=768), K=256
  k_mfma_gemm<0, 1, 0><<<dim3(12, 256), 256, 0, stream>>>(srcb, qkvT, nullptr, QKVb, nullptr, kN, 256, 768);
  // 7. attention
  k_attn<<<512, 256, 0, stream>>>(QKVb, pts, idxb, bq, bk, bv, aoInB);
  // 8. ao = attn_out @ wo + bo (bf16), K=256
  k_mfma_gemm<0, 1, 0><<<dim3(4, 256), 256, 0, stream>>>(aoInB, woT, bo, aoB, nullptr, kN, 256, 256);
  // 9. h1 = relu(ao @ fw1 + fb1) (bf16), K=256
  k_mfma_gemm<1, 1, 0><<<dim3(8, 256), 256, 0, stream>>>(aoB, fw1T, fb1, h1B, nullptr, kN, 256, 512);
  // 10. x = ao + (h1 @ fw2 + fb2) (bf16), K=512
  k_mfma_gemm<0, 1, 1><<<dim3(4, 256), 256, 0, stream>>>(h1B, fw2T, fb2, xBb, aoB, kN, 512, 256);
  // 11. LN -> A2[:,0:256]
  k_ln<<<4096, 256, 0, stream>>>(xBb, lng, lnb, A2);
  // 12. f GEMM (K=320, 5x64) + fused BN stats
  k_fgemm<<<256, 256, 0, stream>>>(A2, W2f, bbf, fB, pS, pQ);
  // 13. BN finalize (redundant per block) + apply + relu -> out
  k_bnapply<<<1024, 256, 0, stream>>>(fB, pS, pQ, bng, bnb, out);
}

// Round 13
// 247.196 us; speedup vs baseline: 1.0135x; 1.0135x over previous
//
#include <hip/hip_runtime.h>
#include <stdint.h>

typedef unsigned short u16;
typedef unsigned int   u32;
typedef __attribute__((ext_vector_type(8))) short short8;
typedef __attribute__((ext_vector_type(4))) float f32x4;

static constexpr int kN = 16384;
static constexpr float kEPS = 1e-5f;

__device__ __forceinline__ u16 f2bf(float x) {
  u32 u = __float_as_uint(x);
  u32 r = (u + 0x7fffu + ((u >> 16) & 1u)) >> 16;
  return (u16)r;
}
__device__ __forceinline__ float bf2f(u16 x) {
  return __uint_as_float(((u32)x) << 16);
}
__device__ __forceinline__ void ldbf8(const u16* p, float* o) {
  uint4 v = *(const uint4*)p;
  o[0] = __uint_as_float(v.x << 16);  o[1] = __uint_as_float(v.x & 0xffff0000u);
  o[2] = __uint_as_float(v.y << 16);  o[3] = __uint_as_float(v.y & 0xffff0000u);
  o[4] = __uint_as_float(v.z << 16);  o[5] = __uint_as_float(v.z & 0xffff0000u);
  o[6] = __uint_as_float(v.w << 16);  o[7] = __uint_as_float(v.w & 0xffff0000u);
}
__device__ __forceinline__ void gll16(const u16* g, u16* l) {
  __builtin_amdgcn_global_load_lds(
      (const __attribute__((address_space(1))) void*)g,
      (__attribute__((address_space(3))) void*)l, 16, 0, 0);
}

// ================= fused setup: zero | weight cast+transpose | pbc+W2f | prep =================
struct WSet {
  const float* s[8]; u16* d[8];
  int K[8]; int N[8]; int dstride[8]; int coff[8];
};

__global__ __launch_bounds__(256) void k_setup(WSet ws,
                                               u32* __restrict__ zero_area,
                                               const float* __restrict__ proj_b,
                                               const float* __restrict__ pe_b2,
                                               float* __restrict__ pbc,
                                               const float* __restrict__ uw1,
                                               const float* __restrict__ ub1,
                                               const float* __restrict__ uw2,
                                               const float* __restrict__ ub2,
                                               u16* __restrict__ W2f,
                                               float* __restrict__ bbf,
                                               const int* __restrict__ coords,
                                               const float* __restrict__ feats,
                                               const float* __restrict__ pw1,
                                               const float* __restrict__ pb1,
                                               u16* __restrict__ A1,
                                               u16* __restrict__ A2) {
  int w = blockIdx.y;
  if (w == 8) {  // zero: cnt, cursor, pS, pQ
    int idx = blockIdx.x * 256 + threadIdx.x;
    if (idx < 33088) zero_area[idx] = 0u;
    return;
  }
  if (w == 9) {  // pbc + fused tail weight
    int bx = blockIdx.x;
    if (bx == 0) {
      pbc[threadIdx.x] = proj_b[threadIdx.x] + pe_b2[threadIdx.x];
    } else if (bx < 65) {
      int n = bx - 1;          // 0..63
      int k = threadIdx.x;     // 0..255
      float s = 0.f;
      for (int j = 0; j < 64; j++) s += uw1[k * 64 + j] * uw2[(64 + j) * 64 + n];
      W2f[n * 320 + k] = f2bf(s);
      if (k < 64) W2f[n * 320 + 256 + k] = f2bf(uw2[k * 64 + n]);
      if (k == 0) {
        float b = ub2[n];
        for (int j = 0; j < 64; j++) b += ub1[j] * uw2[(64 + j) * 64 + n];
        bbf[n] = b;
      }
    }
    return;
  }
  if (w == 10) {  // prep: A1 = [feats | relu(PE hidden)] (Nx192); A2[:,256:320] = feats bf16
    int r0 = blockIdx.x * 32;
#pragma unroll
    for (int s = 0; s < 3; s++) {
      int j = threadIdx.x + s * 256;  // 0..767 = 32 rows x 24 segs
      int row = j / 24, seg = j % 24;
      int n = r0 + row;
      u16 o[8];
      if (seg < 8) {
        const float* fp = feats + (size_t)n * 64 + seg * 8;
        float4 a = *(const float4*)fp;
        float4 b = *(const float4*)(fp + 4);
        o[0] = f2bf(a.x); o[1] = f2bf(a.y); o[2] = f2bf(a.z); o[3] = f2bf(a.w);
        o[4] = f2bf(b.x); o[5] = f2bf(b.y); o[6] = f2bf(b.z); o[7] = f2bf(b.w);
        *(uint4*)(A2 + (size_t)n * 320 + 256 + seg * 8) = *(uint4*)o;
      } else {
        int jj0 = (seg - 8) * 8;
        float x0 = (float)coords[n * 3 + 0] * (1.f / 127.f);
        float x1 = (float)coords[n * 3 + 1] * (1.f / 127.f);
        float x2 = (float)coords[n * 3 + 2] * (1.f / 127.f);
#pragma unroll
        for (int u = 0; u < 8; u++) {
          int jj = jj0 + u;
          float hv = pb1[jj] + x0 * pw1[jj] + x1 * pw1[128 + jj] + x2 * pw1[256 + jj];
          o[u] = f2bf(fmaxf(hv, 0.f));
        }
      }
      *(uint4*)(A1 + (size_t)n * 192 + seg * 8) = *(uint4*)o;
    }
    return;
  }
  // weight cast+transpose: S (K x N fp32) -> D[n*dstride+coff+k] bf16
  const float* S = ws.s[w]; u16* D = ws.d[w];
  int K = ws.K[w], N = ws.N[w], ds = ws.dstride[w], co = ws.coff[w];
  int ntx = N >> 5, tiles = ntx * (K >> 5);
  int t = blockIdx.x;
  if (t >= tiles) return;
  int n0 = (t % ntx) * 32, k0 = (t / ntx) * 32;
  __shared__ float st[32][33];
  int tr = threadIdx.x >> 3, tc4 = (threadIdx.x & 7) * 4;
  float4 v = *(const float4*)(S + (size_t)(k0 + tr) * N + n0 + tc4);
  st[tc4 + 0][tr] = v.x; st[tc4 + 1][tr] = v.y;
  st[tc4 + 2][tr] = v.z; st[tc4 + 3][tr] = v.w;
  __syncthreads();
  u16 o4[4];
  o4[0] = f2bf(st[tr][tc4 + 0]); o4[1] = f2bf(st[tr][tc4 + 1]);
  o4[2] = f2bf(st[tr][tc4 + 2]); o4[3] = f2bf(st[tr][tc4 + 3]);
  *(uint2*)(D + (size_t)(n0 + tr) * ds + co + k0 + tc4) = *(uint2*)o4;
}

// ================= neighbor grid (cells = x*128+y), 4 separate kernels =================

__global__ __launch_bounds__(256) void k_hist(const int* __restrict__ coords,
                                              u32* __restrict__ cnt) {
  int n = blockIdx.x * 256 + threadIdx.x;
  int c = coords[n * 3] * 128 + coords[n * 3 + 1];
  atomicAdd(&cnt[c], 1u);
}

__global__ __launch_bounds__(256) void k_scan(const u32* __restrict__ cnt,
                                              u32* __restrict__ startb) {
  __shared__ u32 tots[256];
  int t = threadIdx.x;
  int base = t * 64;
  u32 s = 0;
  for (int i = 0; i < 64; i++) s += cnt[base + i];
  tots[t] = s;
  __syncthreads();
  if (t == 0) {
    u32 run = 0;
    for (int i = 0; i < 256; i++) { u32 v = tots[i]; tots[i] = run; run += v; }
  }
  __syncthreads();
  u32 run = tots[t];
  for (int i = 0; i < 64; i++) { startb[base + i] = run; run += cnt[base + i]; }
}

__global__ __launch_bounds__(256) void k_scatter(const int* __restrict__ coords,
                                                 const u32* __restrict__ startb,
                                                 u32* __restrict__ cursor,
                                                 u32* __restrict__ pts) {
  int n = blockIdx.x * 256 + threadIdx.x;
  int x = coords[n * 3], y = coords[n * 3 + 1], z = coords[n * 3 + 2];
  int c = x * 128 + y;
  u32 slot = atomicAdd(&cursor[c], 1u);
  pts[startb[c] + slot] = ((u32)z << 14) | (u32)n;  // z:7b | idx:14b
}

__global__ __launch_bounds__(256) void k_select(const int* __restrict__ coords,
                                                const u32* __restrict__ startb,
                                                const u32* __restrict__ cnt,
                                                const u32* __restrict__ pts,
                                                int* __restrict__ idxo) {
  int n = blockIdx.x * 256 + threadIdx.x;
  int x = coords[n * 3], y = coords[n * 3 + 1], z = coords[n * 3 + 2];
  u32 best[16];
#pragma unroll
  for (int j = 0; j < 16; j++) best[j] = 0xFFFFFFFFu;
  const int dxs[13] = {0, -1, 1, 0, 0, -2, 2, 0, 0, -1, -1, 1, 1};
  const int dys[13] = {0, 0, 0, -1, 1, 0, 0, -2, 2, -1, 1, -1, 1};
  const int dbs[13] = {0, 1, 1, 1, 1, 2, 2, 2, 2, 2, 2, 2, 2};
#pragma unroll
  for (int t = 0; t < 13; t++) {
    int xx = x + dxs[t], yy = y + dys[t];
    if (xx < 0 || xx > 127 || yy < 0 || yy > 127) continue;
    int c = xx * 128 + yy;
    u32 s0 = startb[c], e0 = s0 + cnt[c];
    for (u32 i = s0; i < e0; ++i) {
      u32 p = pts[i];
      int zq = (int)(p >> 14);
      int id = (int)(p & 16383u);
      int az = z - zq; az = az < 0 ? -az : az;
      int dd = dbs[t] + az;
      u32 key = (dd <= 2) ? (((u32)dd << 14) | (u32)id) : 0xFFFFFFFFu;
#pragma unroll
      for (int j = 0; j < 16; j++) {
        u32 lo = min(best[j], key);
        u32 hi = max(best[j], key);
        best[j] = lo; key = hi;
      }
    }
  }
#pragma unroll
  for (int j = 0; j < 16; j++)
    idxo[n * 16 + j] = (best[j] == 0xFFFFFFFFu) ? -1 : (int)(best[j] & 16383u);
}

// ================= bf16 MFMA GEMM: C = A(MxK) @ WT(NxK)^T =================
// 64x64 tile, BK=64 via paired 32-chunk staging buffers (half the barriers of BK=32).
// 256 threads (4 waves 2x2). OUTBF: 1=bf16. ADD: += bf16 Addp. K % 64 == 0.
template <int ACT, int OUTBF, int ADD>
__global__ __launch_bounds__(256) void k_mfma_gemm(
    const u16* __restrict__ A, const u16* __restrict__ WT,
    const float* __restrict__ bias,
    void* __restrict__ Cout,
    const u16* __restrict__ Addp,
    int M, int K, int N) {
  __shared__ __align__(16) u16 As[2][64 * 32];
  __shared__ __align__(16) u16 Bs[2][64 * 32];
  const int tid = threadIdx.x;
  const int wave = tid >> 6, lane = tid & 63;
  const int bm = blockIdx.y * 64, bn = blockIdx.x * 64;
  const int wr = (wave >> 1) * 32, wc = (wave & 1) * 32;
  const int g = wave * 64 + lane;
  const int grow = g >> 2, gko = (g & 3) * 8;
  const int fr = lane & 15, fk = (lane >> 4) * 8, rq = (lane >> 4) * 4;

  f32x4 acc[2][2];
#pragma unroll
  for (int i = 0; i < 2; i++)
#pragma unroll
    for (int j = 0; j < 2; j++)
#pragma unroll
      for (int r = 0; r < 4; r++) acc[i][j][r] = 0.f;

  for (int k0 = 0; k0 < K; k0 += 64) {
#pragma unroll
    for (int h = 0; h < 2; h++) {
      gll16(A + (size_t)(bm + grow) * K + k0 + h * 32 + gko, As[h] + g * 8);
      gll16(WT + (size_t)(bn + grow) * K + k0 + h * 32 + gko, Bs[h] + g * 8);
    }
    __syncthreads();
#pragma unroll
    for (int h = 0; h < 2; h++) {
      short8 af[2], bg[2];
#pragma unroll
      for (int i = 0; i < 2; i++)
        af[i] = *(const short8*)&As[h][(wr + i * 16 + fr) * 32 + fk];
#pragma unroll
      for (int j = 0; j < 2; j++)
        bg[j] = *(const short8*)&Bs[h][(wc + j * 16 + fr) * 32 + fk];
#pragma unroll
      for (int i = 0; i < 2; i++)
#pragma unroll
        for (int j = 0; j < 2; j++)
          acc[i][j] = __builtin_amdgcn_mfma_f32_16x16x32_bf16(af[i], bg[j], acc[i][j], 0, 0, 0);
    }
    __syncthreads();
  }

#pragma unroll
  for (int j = 0; j < 2; j++) {
    int cc = bn + wc + j * 16 + fr;
    float bval = bias ? bias[cc] : 0.f;
#pragma unroll
    for (int i = 0; i < 2; i++) {
      int rbase = bm + wr + i * 16 + rq;
#pragma unroll
      for (int r = 0; r < 4; r++) {
        float v = acc[i][j][r] + bval;
        size_t o = (size_t)(rbase + r) * N + cc;
        if (ADD) v += bf2f(Addp[o]);
        if (ACT) v = fmaxf(v, 0.f);
        if (OUTBF) ((u16*)Cout)[o] = f2bf(v);
        else       ((float*)Cout)[o] = v;
      }
    }
  }
}

// ================= attention: one thread per (query, head), cell-sorted order =================
__global__ __launch_bounds__(256) void k_attn(const u16* __restrict__ QKV,
                                              const u32* __restrict__ pts,
                                              const int* __restrict__ idx,
                                              const float* __restrict__ bq,
                                              const float* __restrict__ bk,
                                              const float* __restrict__ bv,
                                              u16* __restrict__ outp) {
  int gid = blockIdx.x * 256 + threadIdx.x;
  int n = (int)(pts[gid >> 3] & 16383u), h = gid & 7;
  const int* ip = idx + n * 16;
  const int hb = h * 32;
  float q[32];
  {
    int i0 = ip[0];  // slot0: dist 0 — always valid
    const u16* qp = QKV + (size_t)i0 * 768 + hb;
#pragma unroll
    for (int j = 0; j < 32; j += 8) ldbf8(qp + j, &q[j]);
#pragma unroll
    for (int j = 0; j < 32; j++) q[j] += bq[hb + j];
  }
  float qbk = 0.f;
#pragma unroll
  for (int j = 0; j < 32; j++) qbk += q[j] * bk[hb + j];
  float s[16]; int ii[16];
#pragma unroll
  for (int m = 0; m < 16; m++) {
    int i = ip[m]; ii[m] = i;
    float d = qbk;
    if (i >= 0) {
      const u16* kp = QKV + (size_t)i * 768 + 256 + hb;
      float kv[32];
#pragma unroll
      for (int j = 0; j < 32; j += 8) ldbf8(kp + j, &kv[j]);
#pragma unroll
      for (int j = 0; j < 32; j++) d += q[j] * kv[j];
    }
    s[m] = d * 0.17677669529663689f;  // 1/sqrt(32)
  }
  float mx = s[0];
#pragma unroll
  for (int m = 1; m < 16; m++) mx = fmaxf(mx, s[m]);
  float sum = 0.f;
#pragma unroll
  for (int m = 0; m < 16; m++) { s[m] = __expf(s[m] - mx); sum += s[m]; }
  float inv = 1.f / sum;
  float o[32];
#pragma unroll
  for (int j = 0; j < 32; j++) o[j] = 0.f;
#pragma unroll
  for (int m = 0; m < 16; m++) {
    if (ii[m] >= 0) {
      const u16* vp = QKV + (size_t)ii[m] * 768 + 512 + hb;
      float vv[32];
#pragma unroll
      for (int j = 0; j < 32; j += 8) ldbf8(vp + j, &vv[j]);
#pragma unroll
      for (int j = 0; j < 32; j++) o[j] += s[m] * vv[j];
    }
  }
  u16* op = outp + (size_t)n * 256 + hb;
#pragma unroll
  for (int j = 0; j < 32; j += 8) {
    u16 tmp[8];
#pragma unroll
    for (int jj = 0; jj < 8; jj++) tmp[jj] = f2bf(o[j + jj] * inv + bv[hb + j + jj]);
    *(uint4*)(op + j) = *(uint4*)tmp;
  }
}

// ================= layernorm over D=256 (bf16 in), one wave per row, bf16 -> A2[:,0:256] =================
__global__ __launch_bounds__(256) void k_ln(const u16* __restrict__ xx,
                                            const float* __restrict__ g,
                                            const float* __restrict__ b,
                                            u16* __restrict__ A2) {
  int row = blockIdx.x * 4 + (threadIdx.x >> 6);
  int lane = threadIdx.x & 63;
  uint2 raw = *(const uint2*)(xx + (size_t)row * 256 + lane * 4);
  float x0 = __uint_as_float(raw.x << 16), x1 = __uint_as_float(raw.x & 0xffff0000u);
  float x2 = __uint_as_float(raw.y << 16), x3 = __uint_as_float(raw.y & 0xffff0000u);
  float sm = x0 + x1 + x2 + x3;
#pragma unroll
  for (int off = 1; off < 64; off <<= 1) sm += __shfl_xor(sm, off);
  float mu = sm * (1.f / 256.f);
  float d0 = x0 - mu, d1 = x1 - mu, d2 = x2 - mu, d3 = x3 - mu;
  float sq = d0 * d0 + d1 * d1 + d2 * d2 + d3 * d3;
#pragma unroll
  for (int off = 1; off < 64; off <<= 1) sq += __shfl_xor(sq, off);
  float rstd = rsqrtf(sq * (1.f / 256.f) + kEPS);
  float4 gv = *(const float4*)(g + lane * 4);
  float4 bv4 = *(const float4*)(b + lane * 4);
  u16 o[4];
  o[0] = f2bf(d0 * rstd * gv.x + bv4.x); o[1] = f2bf(d1 * rstd * gv.y + bv4.y);
  o[2] = f2bf(d2 * rstd * gv.z + bv4.z); o[3] = f2bf(d3 * rstd * gv.w + bv4.w);
  *(uint2*)(A2 + (size_t)row * 320 + lane * 4) = *(uint2*)o;
}

// ================= f = A2 @ W2f^T + bbf -> fB + fused BN column stats =================
// K = 320 = 5 x 64 exactly.
__global__ __launch_bounds__(256) void k_fgemm(const u16* __restrict__ A2,
                                               const u16* __restrict__ W2f,
                                               const float* __restrict__ bbf,
                                               float* __restrict__ fB,
                                               float* __restrict__ pS,
                                               float* __restrict__ pQ) {
  __shared__ __align__(16) u16 As[2][2048];
  __shared__ __align__(16) u16 Bs[2][2048];
  __shared__ float colS[64][2], colQ[64][2];
  const int tid = threadIdx.x;
  const int wave = tid >> 6, lane = tid & 63;
  const int bm = blockIdx.x * 64;
  const int wr = (wave >> 1) * 32, wc = (wave & 1) * 32;
  const int fr = lane & 15, fk = (lane >> 4) * 8, rq = (lane >> 4) * 4;
  const int g = wave * 64 + lane;
  const int grow = g >> 2, gko = (g & 3) * 8;

  f32x4 acc[2][2];
#pragma unroll
  for (int i = 0; i < 2; i++)
#pragma unroll
    for (int j = 0; j < 2; j++)
#pragma unroll
      for (int r = 0; r < 4; r++) acc[i][j][r] = 0.f;
  for (int k0 = 0; k0 < 320; k0 += 64) {
#pragma unroll
    for (int h = 0; h < 2; h++) {
      gll16(A2 + (size_t)(bm + grow) * 320 + k0 + h * 32 + gko, As[h] + g * 8);
      gll16(W2f + (size_t)grow * 320 + k0 + h * 32 + gko, Bs[h] + g * 8);
    }
    __syncthreads();
#pragma unroll
    for (int h = 0; h < 2; h++) {
      short8 af[2], bg[2];
#pragma unroll
      for (int i = 0; i < 2; i++)
        af[i] = *(const short8*)&As[h][(wr + i * 16 + fr) * 32 + fk];
#pragma unroll
      for (int j = 0; j < 2; j++)
        bg[j] = *(const short8*)&Bs[h][(wc + j * 16 + fr) * 32 + fk];
#pragma unroll
      for (int i = 0; i < 2; i++)
#pragma unroll
        for (int j = 0; j < 2; j++)
          acc[i][j] = __builtin_amdgcn_mfma_f32_16x16x32_bf16(af[i], bg[j], acc[i][j], 0, 0, 0);
    }
    __syncthreads();
  }
  float cS[2] = {0.f, 0.f}, cQ[2] = {0.f, 0.f};
#pragma unroll
  for (int j = 0; j < 2; j++) {
    int col = wc + j * 16 + fr;
    float bv = bbf[col];
#pragma unroll
    for (int i = 0; i < 2; i++) {
      int rbase = bm + wr + i * 16 + rq;
#pragma unroll
      for (int r = 0; r < 4; r++) {
        float v = acc[i][j][r] + bv;
        fB[(size_t)(rbase + r) * 64 + col] = v;
        cS[j] += v; cQ[j] += v * v;
      }
    }
  }
#pragma unroll
  for (int off = 16; off < 64; off <<= 1) {
#pragma unroll
    for (int j = 0; j < 2; j++) {
      cS[j] += __shfl_xor(cS[j], off);
      cQ[j] += __shfl_xor(cQ[j], off);
    }
  }
  if ((lane >> 4) == 0) {
#pragma unroll
    for (int j = 0; j < 2; j++) {
      colS[wc + j * 16 + fr][wave >> 1] = cS[j];
      colQ[wc + j * 16 + fr][wave >> 1] = cQ[j];
    }
  }
  __syncthreads();
  if (tid < 64) {
    atomicAdd(&pS[tid], colS[tid][0] + colS[tid][1]);
    atomicAdd(&pQ[tid], colQ[tid][0] + colQ[tid][1]);
  }
}

__global__ __launch_bounds__(64) void k_bnfin(const float* __restrict__ pS,
                                              const float* __restrict__ pQ,
                                              const float* __restrict__ g,
                                              const float* __restrict__ b,
                                              float* __restrict__ coef,
                                              float* __restrict__ shift) {
  int c = threadIdx.x;
  float S = pS[c], Q = pQ[c];
  float m = S * (1.f / 16384.f);
  float var = Q * (1.f / 16384.f) - m * m;
  float cf = rsqrtf(var + kEPS) * g[c];
  coef[c] = cf;
  shift[c] = b[c] - m * cf;
}

__global__ __launch_bounds__(256) void k_bnapply(const float* __restrict__ f,
                                                 const float* __restrict__ coef,
                                                 const float* __restrict__ shift,
                                                 float* __restrict__ out) {
  int gid = blockIdx.x * 256 + threadIdx.x;
  int e = gid * 4, col = e & 63;
  float4 v = *(const float4*)(f + e);
  float4 cf = *(const float4*)(coef + col);
  float4 sh = *(const float4*)(shift + col);
  float4 o;
  o.x = fmaxf(v.x * cf.x + sh.x, 0.f);
  o.y = fmaxf(v.y * cf.y + sh.y, 0.f);
  o.z = fmaxf(v.z * cf.z + sh.z, 0.f);
  o.w = fmaxf(v.w * cf.w + sh.w, 0.f);
  *(float4*)(out + e) = o;
}

// ================= launch =================
extern "C" void kernel_launch(void* const* d_in, const int* in_sizes, int n_in,
                              void* d_out, int out_size, void* d_ws, size_t ws_size,
                              hipStream_t stream) {
  (void)in_sizes; (void)n_in; (void)out_size; (void)ws_size;
  const int*   coords = (const int*)d_in[0];
  const float* feats  = (const float*)d_in[1];
  const float* pe_w1  = (const float*)d_in[2];
  const float* pe_b1  = (const float*)d_in[3];
  const float* pe_w2  = (const float*)d_in[4];
  const float* pe_b2  = (const float*)d_in[5];
  const float* proj_w = (const float*)d_in[6];
  const float* proj_b = (const float*)d_in[7];
  const float* wq  = (const float*)d_in[8];
  const float* bq  = (const float*)d_in[9];
  const float* wk  = (const float*)d_in[10];
  const float* bk  = (const float*)d_in[11];
  const float* wv  = (const float*)d_in[12];
  const float* bv  = (const float*)d_in[13];
  const float* wo  = (const float*)d_in[14];
  const float* bo  = (const float*)d_in[15];
  const float* fw1 = (const float*)d_in[16];
  const float* fb1 = (const float*)d_in[17];
  const float* fw2 = (const float*)d_in[18];
  const float* fb2 = (const float*)d_in[19];
  const float* lng = (const float*)d_in[20];
  const float* lnb = (const float*)d_in[21];
  const float* uw1 = (const float*)d_in[22];
  const float* ub1 = (const float*)d_in[23];
  const float* uw2 = (const float*)d_in[24];
  const float* ub2 = (const float*)d_in[25];
  const float* bng = (const float*)d_in[26];
  const float* bnb = (const float*)d_in[27];
  float* out = (float*)d_out;

  char* Wc = (char*)d_ws;
  const size_t MB = 1u << 20;
  u16*   A1    = (u16*)(Wc + 0 * MB);    // 6MB
  u16*   srcb  = (u16*)(Wc + 6 * MB);    // 8MB
  u16*   QKVb  = (u16*)(Wc + 14 * MB);   // 24MB
  u16*   aoInB = (u16*)(Wc + 38 * MB);   // 8MB
  u16*   aoB   = (u16*)(Wc + 46 * MB);   // 8MB
  u16*   h1B   = (u16*)(Wc + 54 * MB);   // 16MB
  u16*   xBb   = (u16*)(Wc + 70 * MB);   // 8MB
  u16*   A2    = (u16*)(Wc + 78 * MB);   // 10MB [y | feats]
  float* fB    = (float*)(Wc + 0 * MB);  // 4MB over dead A1

  u16* qkvT  = (u16*)(Wc + 88 * MB);     // 768 x 256
  u16* woT   = qkvT + 196608;            // 256 x 256
  u16* fw1T  = woT + 65536;              // 512 x 256
  u16* fw2T  = fw1T + 131072;            // 256 x 512
  u16* W1T   = fw2T + 131072;            // 256 x 192
  u16* W2f   = W1T + 49152;              // 64 x 320
  float* pbc = (float*)(W2f + 20480);    // 256
  float* bbf = pbc + 256;                // 64

  u32* Z      = (u32*)(Wc + 90 * MB);
  u32* cnt    = Z;                        // 16384  (zeroed)
  u32* cursor = Z + 16384;                // 16384  (zeroed)
  float* pS   = (float*)(Z + 32768);      // 64     (zeroed)
  float* pQ   = (float*)(Z + 32832);      // 64     (zeroed)
  float* coefb = (float*)(Z + 32912);     // 64
  float* shb   = coefb + 64;              // 64
  u32* startb = Z + 33280;                // 16384
  u32* pts    = Z + 49664;                // 16384
  int* idxb   = (int*)(Z + 66048);        // N*16

  WSet ws;
  ws.s[0] = wq;     ws.d[0] = qkvT;          ws.K[0] = 256; ws.N[0] = 256; ws.dstride[0] = 256; ws.coff[0] = 0;
  ws.s[1] = wk;     ws.d[1] = qkvT + 65536;  ws.K[1] = 256; ws.N[1] = 256; ws.dstride[1] = 256; ws.coff[1] = 0;
  ws.s[2] = wv;     ws.d[2] = qkvT + 131072; ws.K[2] = 256; ws.N[2] = 256; ws.dstride[2] = 256; ws.coff[2] = 0;
  ws.s[3] = wo;     ws.d[3] = woT;           ws.K[3] = 256; ws.N[3] = 256; ws.dstride[3] = 256; ws.coff[3] = 0;
  ws.s[4] = fw1;    ws.d[4] = fw1T;          ws.K[4] = 256; ws.N[4] = 512; ws.dstride[4] = 256; ws.coff[4] = 0;
  ws.s[5] = fw2;    ws.d[5] = fw2T;          ws.K[5] = 512; ws.N[5] = 256; ws.dstride[5] = 512; ws.coff[5] = 0;
  ws.s[6] = proj_w; ws.d[6] = W1T;           ws.K[6] = 64;  ws.N[6] = 256; ws.dstride[6] = 192; ws.coff[6] = 0;
  ws.s[7] = pe_w2;  ws.d[7] = W1T;           ws.K[7] = 128; ws.N[7] = 256; ws.dstride[7] = 192; ws.coff[7] = 64;

  // 1. setup: zero ctl, weight casts, pbc/W2f/bbf, prep(A1 + A2 feats half)
  k_setup<<<dim3(512, 11), 256, 0, stream>>>(ws, Z, proj_b, pe_b2, pbc,
                                             uw1, ub1, uw2, ub2, W2f, bbf,
                                             coords, feats, pe_w1, pe_b1, A1, A2);
  // 2-5. neighbor pipeline
  k_hist<<<64, 256, 0, stream>>>(coords, cnt);
  k_scan<<<1, 256, 0, stream>>>(cnt, startb);
  k_scatter<<<64, 256, 0, stream>>>(coords, startb, cursor, pts);
  k_select<<<64, 256, 0, stream>>>(coords, startb, cnt, pts, idxb);
  // 6. src = A1 @ W1T^T + pbc (bf16), K=192
  k_mfma_gemm<0, 1, 0><<<dim3(4, 256), 256, 0, stream>>>(A1, W1T, pbc, srcb, nullptr, kN, 192, 256);
  // 7. QKV fused (N=768), K=256
  k_mfma_gemm<0, 1, 0><<<dim3(12, 256), 256, 0, stream>>>(srcb, qkvT, nullptr, QKVb, nullptr, kN, 256, 768);
  // 8. attention
  k_attn<<<512, 256, 0, stream>>>(QKVb, pts, idxb, bq, bk, bv, aoInB);
  // 9. ao = attn_out @ wo + bo (bf16), K=256
  k_mfma_gemm<0, 1, 0><<<dim3(4, 256), 256, 0, stream>>>(aoInB, woT, bo, aoB, nullptr, kN, 256, 256);
  // 10. h1 = relu(ao @ fw1 + fb1) (bf16), K=256
  k_mfma_gemm<1, 1, 0><<<dim3(8, 256), 256, 0, stream>>>(aoB, fw1T, fb1, h1B, nullptr, kN, 256, 512);
  // 11. x = ao + (h1 @ fw2 + fb2) (bf16), K=512
  k_mfma_gemm<0, 1, 1><<<dim3(4, 256), 256, 0, stream>>>(h1B, fw2T, fb2, xBb, aoB, kN, 512, 256);
  // 12. LN -> A2[:,0:256]
  k_ln<<<4096, 256, 0, stream>>>(xBb, lng, lnb, A2);
  // 13. f GEMM (K=320, 5x64) + fused BN stats
  k_fgemm<<<256, 256, 0, stream>>>(A2, W2f, bbf, fB, pS, pQ);
  // 14-15. BN finalize + apply
  k_bnfin<<<1, 64, 0, stream>>>(pS, pQ, bng, bnb, coefb, shb);
  k_bnapply<<<1024, 256, 0, stream>>>(fB, coefb, shb, out);
}